// Round 18
// baseline (302.744 us; speedup 1.0000x reference)
//
#include <hip/hip_runtime.h>
#include <hip/hip_bf16.h>

#define NNODES 100000
#define DIN    256
#define NHID   128
#define EPS    1e-5f
#define SHIFT  9
#define NB2    ((NNODES + 511) >> SHIFT)    // 196 buckets of 512 dst
#define BCAP2  9216                         // mean 8163 + ~11 sigma
#define CURPAD 16                           // global counters padded to 64B
#define PH     2048                         // edges per partition phase

typedef __attribute__((ext_vector_type(8))) short short8v;  // 8 x bf16
typedef __attribute__((ext_vector_type(4))) float f32x4;

static __device__ __forceinline__ unsigned short f2bf(float v) {
    __hip_bfloat16 b = __float2bfloat16(v);
    return *reinterpret_cast<unsigned short*>(&b);
}
static __device__ __forceinline__ float bfhi2f(unsigned int u) {
    union { unsigned int i; float f; } x; x.i = u & 0xFFFF0000u; return x.f;
}
static __device__ __forceinline__ float bflo2f(unsigned int u) {
    union { unsigned int i; float f; } x; x.i = u << 16; return x.f;
}

// ---------------- Prep: W transposes + counter/stat zeroing ----------------
__global__ __launch_bounds__(256) void prep_kernel(const float* __restrict__ W1,
                                                   const float* __restrict__ W2,
                                                   unsigned short* __restrict__ Wt1,
                                                   unsigned short* __restrict__ Wt2,
                                                   int* __restrict__ gcur,
                                                   float* __restrict__ sums) {
    int i = blockIdx.x * 256 + threadIdx.x;
    if (i < DIN * NHID) {
        const int k = i >> 7, c = i & 127;
        Wt1[c * DIN + k] = f2bf(W1[i]);
        return;
    }
    i -= DIN * NHID;
    if (i < NHID * NHID) {
        const int k = i >> 7, c = i & 127;
        Wt2[c * NHID + k] = f2bf(W2[i]);
        return;
    }
    i -= NHID * NHID;
    if (i < NB2 * CURPAD) { gcur[i] = 0; return; }
    i -= NB2 * CURPAD;
    if (i < 512) sums[i] = 0.f;
}

// ---------------- Fused: GEMM1 (blocks < ngemm) || edge partition (rest) ----------------
// GEMM: BM=64 tile, 2x2 waves of 32r x 64c, double-buffered LDS A (fp32 x -> bf16).
__global__ __launch_bounds__(256) void gemm1_part_kernel(
    const float* __restrict__ Af, const unsigned short* __restrict__ Wtb,
    unsigned short* __restrict__ C, int M, int ngemm,
    const int* __restrict__ src, const int* __restrict__ dst,
    const float* __restrict__ w, int* __restrict__ gcur,
    int2* __restrict__ bstage, int E) {
    struct GemmS { unsigned short As[2][64 * 40]; };
    struct PartS {
        int2 staged[PH];
        int hist[NB2], scn[NB2], cur[NB2], gbase[NB2];
        int pscan[256];
        unsigned char aux[PH];
    };
    __shared__ union { GemmS g; PartS p; } sm;

    const int t = threadIdx.x;
    if (blockIdx.x < ngemm) {
        constexpr int K = DIN;
        constexpr int NS = K / 32;
        constexpr int PADB = 40;
        const int wid = t >> 6;
        const int lane = t & 63;
        const int wr = wid >> 1, wc = wid & 1;
        const int l15 = lane & 15, g = lane >> 4;
        const int R0 = blockIdx.x * 64;
        const int RW = R0 + wr * 32;
        const int srow = t >> 2;
        const int scol = (t & 3) * 8;

        f32x4 acc[2][4] = {};

        auto STAGE = [&](int s, int buf) {
            const int k0 = s * 32;
            int grow = R0 + srow;
            grow = grow < M ? grow : M - 1;
            const float* p = Af + (size_t)grow * K + k0 + scol;
            const float4 v0 = *reinterpret_cast<const float4*>(p);
            const float4 v1 = *reinterpret_cast<const float4*>(p + 4);
            unsigned short bv[8];
            bv[0] = f2bf(v0.x); bv[1] = f2bf(v0.y); bv[2] = f2bf(v0.z); bv[3] = f2bf(v0.w);
            bv[4] = f2bf(v1.x); bv[5] = f2bf(v1.y); bv[6] = f2bf(v1.z); bv[7] = f2bf(v1.w);
            *reinterpret_cast<uint4*>(&sm.g.As[buf][srow * PADB + scol]) =
                *reinterpret_cast<const uint4*>(bv);
        };

        STAGE(0, 0);
        __syncthreads();

        for (int s = 0; s < NS; ++s) {
            if (s + 1 < NS) STAGE(s + 1, (s + 1) & 1);
            const unsigned short* ab = sm.g.As[s & 1];
            short8v b[4];
#pragma unroll
            for (int n = 0; n < 4; ++n) {
                const int col = wc * 64 + n * 16 + l15;
                b[n] = *reinterpret_cast<const short8v*>(&Wtb[(size_t)col * K + s * 32 + g * 8]);
            }
            short8v a[2];
#pragma unroll
            for (int m = 0; m < 2; ++m) {
                const int row = wr * 32 + m * 16 + l15;
                a[m] = *reinterpret_cast<const short8v*>(&ab[row * PADB + g * 8]);
            }
#pragma unroll
            for (int m = 0; m < 2; ++m)
#pragma unroll
                for (int n = 0; n < 4; ++n)
                    acc[m][n] = __builtin_amdgcn_mfma_f32_16x16x32_bf16(a[m], b[n], acc[m][n], 0, 0, 0);
            __syncthreads();
        }

#pragma unroll
        for (int m = 0; m < 2; ++m) {
#pragma unroll
            for (int q = 0; q < 4; ++q) {
                const int row = RW + m * 16 + g * 4 + q;
                if (row < M) {
                    unsigned short* cp = C + (size_t)row * NHID + wc * 64 + l15;
#pragma unroll
                    for (int n = 0; n < 4; ++n)
                        cp[n * 16] = f2bf(acc[m][n][q]);
                }
            }
        }
    } else {
        // ---- partition path ----
        const int c = blockIdx.x - ngemm;
        const int e0 = c * PH;
        if (e0 >= E) return;
        const int cnt = min(PH, E - e0);
        for (int i = t; i < NB2; i += 256) sm.p.hist[i] = 0;
        __syncthreads();

        int2 pay[8];
        int bk[8];
#pragma unroll
        for (int j = 0; j < 8; ++j) {
            const int i = j * 256 + t;
            bk[j] = -1;
            if (i < cnt) {
                const int e = e0 + i;
                const int d = dst[e];
                bk[j] = d >> SHIFT;
                pay[j].x = src[e] | ((d & 511) << 17);
                pay[j].y = __float_as_int(w[e]);
                atomicAdd(&sm.p.hist[bk[j]], 1);
            }
        }
        __syncthreads();

        sm.p.pscan[t] = (t < NB2) ? sm.p.hist[t] : 0;
        __syncthreads();
        for (int off = 1; off < 256; off <<= 1) {
            const int v = (t >= off) ? sm.p.pscan[t - off] : 0;
            __syncthreads();
            sm.p.pscan[t] += v;
            __syncthreads();
        }
        if (t < NB2) {
            const int ex = sm.p.pscan[t] - sm.p.hist[t];
            sm.p.scn[t] = ex;
            sm.p.cur[t] = ex;
        }
        __syncthreads();

#pragma unroll
        for (int j = 0; j < 8; ++j) {
            if (bk[j] >= 0) {
                const int p = atomicAdd(&sm.p.cur[bk[j]], 1);
                sm.p.staged[p] = pay[j];
                sm.p.aux[p] = (unsigned char)bk[j];
            }
        }
        if (t < NB2 && sm.p.hist[t] > 0)
            sm.p.gbase[t] = atomicAdd(&gcur[t * CURPAD], sm.p.hist[t]);
        __syncthreads();

        for (int i = t; i < cnt; i += 256) {
            const int b = sm.p.aux[i];
            const int p = sm.p.gbase[b] + (i - sm.p.scn[b]);
            if (p < BCAP2) bstage[(size_t)b * BCAP2 + p] = sm.p.staged[i];
        }
    }
}

// ---------------- Pass B: per-bucket exact CSR, 4 blocks per bucket ----------------
// Block k of bucket b: full-bucket hist + prefix-hist of [0, h0) -> disjoint exact
// scatter positions for its quarter [h0, h1). 784 blocks -> ~3/CU (was 196 -> 0.77/CU).
__global__ __launch_bounds__(512) void csr_kernel(const int* __restrict__ gcur,
                                                  const int2* __restrict__ bstage,
                                                  int2* __restrict__ row_be,
                                                  int2* __restrict__ s_iw) {
    const int b = blockIdx.x >> 2;
    const int k = blockIdx.x & 3;
    const int t = threadIdx.x;
    int cnt = gcur[b * CURPAD];
    if (cnt > BCAP2) cnt = BCAP2;
    const int sbase = b * BCAP2;
    const int h0 = (cnt * k) >> 2;
    const int h1 = (cnt * (k + 1)) >> 2;

    __shared__ int hist[512], pre[512], cur[512], part[512];
    hist[t] = 0;
    pre[t] = 0;
    __syncthreads();
    for (int i = t; i < cnt; i += 512) {
        const int l = (bstage[sbase + i].x >> 17) & 511;
        atomicAdd(&hist[l], 1);
        if (i < h0) atomicAdd(&pre[l], 1);
    }
    __syncthreads();

    part[t] = hist[t];
    __syncthreads();
    for (int off = 1; off < 512; off <<= 1) {
        const int v = (t >= off) ? part[t - off] : 0;
        __syncthreads();
        part[t] += v;
        __syncthreads();
    }
    const int excl = part[t] - hist[t];
    cur[t] = excl + pre[t];
    if (k == 0) {
        const int d = (b << SHIFT) + t;
        if (d < NNODES) {
            int2 be;
            be.x = sbase + excl;
            be.y = sbase + part[t];
            row_be[d] = be;
        }
    }
    __syncthreads();

    for (int i = h0 + t; i < h1; i += 512) {
        const int2 e = bstage[sbase + i];
        const int l = (e.x >> 17) & 511;
        const int p = atomicAdd(&cur[l], 1);
        int2 o;
        o.x = e.x & 0x1FFFF;
        o.y = e.y;
        s_iw[sbase + p] = o;
    }
}

// ---------------- Aggregate: 16-lane edge groups, uint4 loads; bf16 output ----------------
__global__ __launch_bounds__(256) void aggregate_kernel(const unsigned short* __restrict__ hb,
                                                        const int2* __restrict__ row_be,
                                                        const int2* __restrict__ s_iw,
                                                        unsigned short* __restrict__ outB, int n) {
    const int wid = (blockIdx.x * 256 + threadIdx.x) >> 6;
    if (wid >= n) return;
    const int lane = threadIdx.x & 63;
    const int grp = lane >> 4;     // edge slot 0..3
    const int l16 = lane & 15;     // col group: cols l16*8 .. +7
    const int2 be = row_be[wid];
    const int end = be.y;

    float acc[8] = {};
    int j = be.x + grp;
    for (; j + 4 < end; j += 8) {
        const int2 e0 = s_iw[j];
        const int2 e1 = s_iw[j + 4];
        const uint4 v0 = *reinterpret_cast<const uint4*>(hb + (size_t)e0.x * NHID + l16 * 8);
        const uint4 v1 = *reinterpret_cast<const uint4*>(hb + (size_t)e1.x * NHID + l16 * 8);
        const float w0 = __int_as_float(e0.y);
        const float w1 = __int_as_float(e1.y);
        acc[0] = fmaf(w0, bflo2f(v0.x), acc[0]); acc[1] = fmaf(w0, bfhi2f(v0.x), acc[1]);
        acc[2] = fmaf(w0, bflo2f(v0.y), acc[2]); acc[3] = fmaf(w0, bfhi2f(v0.y), acc[3]);
        acc[4] = fmaf(w0, bflo2f(v0.z), acc[4]); acc[5] = fmaf(w0, bfhi2f(v0.z), acc[5]);
        acc[6] = fmaf(w0, bflo2f(v0.w), acc[6]); acc[7] = fmaf(w0, bfhi2f(v0.w), acc[7]);
        acc[0] = fmaf(w1, bflo2f(v1.x), acc[0]); acc[1] = fmaf(w1, bfhi2f(v1.x), acc[1]);
        acc[2] = fmaf(w1, bflo2f(v1.y), acc[2]); acc[3] = fmaf(w1, bfhi2f(v1.y), acc[3]);
        acc[4] = fmaf(w1, bflo2f(v1.z), acc[4]); acc[5] = fmaf(w1, bfhi2f(v1.z), acc[5]);
        acc[6] = fmaf(w1, bflo2f(v1.w), acc[6]); acc[7] = fmaf(w1, bfhi2f(v1.w), acc[7]);
    }
    if (j < end) {
        const int2 e0 = s_iw[j];
        const uint4 v0 = *reinterpret_cast<const uint4*>(hb + (size_t)e0.x * NHID + l16 * 8);
        const float w0 = __int_as_float(e0.y);
        acc[0] = fmaf(w0, bflo2f(v0.x), acc[0]); acc[1] = fmaf(w0, bfhi2f(v0.x), acc[1]);
        acc[2] = fmaf(w0, bflo2f(v0.y), acc[2]); acc[3] = fmaf(w0, bfhi2f(v0.y), acc[3]);
        acc[4] = fmaf(w0, bflo2f(v0.z), acc[4]); acc[5] = fmaf(w0, bfhi2f(v0.z), acc[5]);
        acc[6] = fmaf(w0, bflo2f(v0.w), acc[6]); acc[7] = fmaf(w0, bfhi2f(v0.w), acc[7]);
    }
#pragma unroll
    for (int k = 0; k < 8; ++k) {
        acc[k] += __shfl_xor(acc[k], 16, 64);
        acc[k] += __shfl_xor(acc[k], 32, 64);
    }
    if (grp == 0) {
        unsigned short bv[8];
#pragma unroll
        for (int k = 0; k < 8; ++k) bv[k] = f2bf(acc[k]);
        *reinterpret_cast<uint4*>(outB + (size_t)wid * NHID + l16 * 8) =
            *reinterpret_cast<const uint4*>(bv);
    }
}

// ---------------- BN stats over bf16 buffer ----------------
__global__ __launch_bounds__(256) void stats_kernel(const unsigned short* __restrict__ h,
                                                    float* __restrict__ sums, int nrows) {
    const int t = threadIdx.x;
    const int cp = t & 63;
    const int rg = t >> 6;
    float s0 = 0.f, s1 = 0.f, q0 = 0.f, q1 = 0.f;
    for (int r = blockIdx.x * 4 + rg; r < nrows; r += gridDim.x * 4) {
        const unsigned int v = *reinterpret_cast<const unsigned int*>(h + (size_t)r * NHID + cp * 2);
        const float a = bflo2f(v), b = bfhi2f(v);
        s0 += a; q0 = fmaf(a, a, q0);
        s1 += b; q1 = fmaf(b, b, q1);
    }
    __shared__ float ls[4][128], lq[4][128];
    ls[rg][cp * 2] = s0; ls[rg][cp * 2 + 1] = s1;
    lq[rg][cp * 2] = q0; lq[rg][cp * 2 + 1] = q1;
    __syncthreads();
    if (t < 128) {
        atomicAdd(&sums[t], ls[0][t] + ls[1][t] + ls[2][t] + ls[3][t]);
    } else {
        const int c = t - 128;
        atomicAdd(&sums[128 + c], lq[0][c] + lq[1][c] + lq[2][c] + lq[3][c]);
    }
}

// ---------------- GEMM2: bf16 A + fused finalize(BN1) + BN+ReLU at staging ----------------
__global__ __launch_bounds__(256) void mfma_gemm2(const unsigned short* __restrict__ Ab,
                                                  const unsigned short* __restrict__ Wtb,
                                                  const float* __restrict__ sums,
                                                  const float* __restrict__ gamma,
                                                  const float* __restrict__ beta,
                                                  unsigned short* __restrict__ C, int M) {
    constexpr int K = NHID;
    constexpr int NS = K / 32;
    constexpr int PADB = 40;
    __shared__ unsigned short As[2][64 * PADB];
    __shared__ float ssl[256];

    const int t = threadIdx.x;
    if (t < 128) {
        const float invN = 1.0f / (float)NNODES;
        const float mean = sums[t] * invN;
        const float var = sums[128 + t] * invN - mean * mean;
        const float scale = gamma[t] * rsqrtf(var + EPS);
        ssl[t] = scale;
        ssl[128 + t] = beta[t] - mean * scale;
    }
    __syncthreads();

    const int wid = t >> 6;
    const int lane = t & 63;
    const int wr = wid >> 1, wc = wid & 1;
    const int l15 = lane & 15, g = lane >> 4;
    const int R0 = blockIdx.x * 64;
    const int RW = R0 + wr * 32;
    const int srow = t >> 2;
    const int scol = (t & 3) * 8;

    f32x4 acc[2][4] = {};

    auto STAGE = [&](int s, int buf) {
        const int k0 = s * 32;
        int grow = R0 + srow;
        grow = grow < M ? grow : M - 1;
        const uint4 v = *reinterpret_cast<const uint4*>(Ab + (size_t)grow * K + k0 + scol);
        const float f[8] = {bflo2f(v.x), bfhi2f(v.x), bflo2f(v.y), bfhi2f(v.y),
                            bflo2f(v.z), bfhi2f(v.z), bflo2f(v.w), bfhi2f(v.w)};
        const int c0 = k0 + scol;
        unsigned short bv[8];
#pragma unroll
        for (int j = 0; j < 8; ++j)
            bv[j] = f2bf(fmaxf(fmaf(f[j], ssl[c0 + j], ssl[128 + c0 + j]), 0.f));
        *reinterpret_cast<uint4*>(&As[buf][srow * PADB + scol]) =
            *reinterpret_cast<const uint4*>(bv);
    };

    STAGE(0, 0);
    __syncthreads();

    for (int s = 0; s < NS; ++s) {
        if (s + 1 < NS) STAGE(s + 1, (s + 1) & 1);
        const unsigned short* ab = As[s & 1];
        short8v b[4];
#pragma unroll
        for (int n = 0; n < 4; ++n) {
            const int col = wc * 64 + n * 16 + l15;
            b[n] = *reinterpret_cast<const short8v*>(&Wtb[(size_t)col * K + s * 32 + g * 8]);
        }
        short8v a[2];
#pragma unroll
        for (int m = 0; m < 2; ++m) {
            const int row = wr * 32 + m * 16 + l15;
            a[m] = *reinterpret_cast<const short8v*>(&ab[row * PADB + g * 8]);
        }
#pragma unroll
        for (int m = 0; m < 2; ++m)
#pragma unroll
            for (int n = 0; n < 4; ++n)
                acc[m][n] = __builtin_amdgcn_mfma_f32_16x16x32_bf16(a[m], b[n], acc[m][n], 0, 0, 0);
        __syncthreads();
    }

#pragma unroll
    for (int m = 0; m < 2; ++m) {
#pragma unroll
        for (int q = 0; q < 4; ++q) {
            const int row = RW + m * 16 + g * 4 + q;
            if (row < M) {
                unsigned short* cp = C + (size_t)row * NHID + wc * 64 + l15;
#pragma unroll
                for (int n = 0; n < 4; ++n)
                    cp[n * 16] = f2bf(acc[m][n][q]);
            }
        }
    }
}

// ---------------- Final apply: fused finalize(BN2) + BN+ReLU, bf16 in / fp32 out ----------------
__global__ __launch_bounds__(256) void apply_kernel(const unsigned short* __restrict__ aggB,
                                                    const float* __restrict__ sums,
                                                    const float* __restrict__ gamma,
                                                    const float* __restrict__ beta,
                                                    float* __restrict__ out, int n8) {
    __shared__ float ss[256];
    const int t = threadIdx.x;
    if (t < 128) {
        const float invN = 1.0f / (float)NNODES;
        const float mean = sums[t] * invN;
        const float var = sums[128 + t] * invN - mean * mean;
        const float scale = gamma[t] * rsqrtf(var + EPS);
        ss[t] = scale;
        ss[128 + t] = beta[t] - mean * scale;
    }
    __syncthreads();
    const int idx = blockIdx.x * 256 + t;
    if (idx >= n8) return;
    const int c0 = (idx & 15) * 8;
    const uint4 v = reinterpret_cast<const uint4*>(aggB)[idx];
    const float f[8] = {bflo2f(v.x), bfhi2f(v.x), bflo2f(v.y), bfhi2f(v.y),
                        bflo2f(v.z), bfhi2f(v.z), bflo2f(v.w), bfhi2f(v.w)};
    float4 r0, r1;
    r0.x = fmaxf(fmaf(f[0], ss[c0],     ss[128 + c0]),     0.f);
    r0.y = fmaxf(fmaf(f[1], ss[c0 + 1], ss[128 + c0 + 1]), 0.f);
    r0.z = fmaxf(fmaf(f[2], ss[c0 + 2], ss[128 + c0 + 2]), 0.f);
    r0.w = fmaxf(fmaf(f[3], ss[c0 + 3], ss[128 + c0 + 3]), 0.f);
    r1.x = fmaxf(fmaf(f[4], ss[c0 + 4], ss[128 + c0 + 4]), 0.f);
    r1.y = fmaxf(fmaf(f[5], ss[c0 + 5], ss[128 + c0 + 5]), 0.f);
    r1.z = fmaxf(fmaf(f[6], ss[c0 + 6], ss[128 + c0 + 6]), 0.f);
    r1.w = fmaxf(fmaf(f[7], ss[c0 + 7], ss[128 + c0 + 7]), 0.f);
    reinterpret_cast<float4*>(out)[idx * 2] = r0;
    reinterpret_cast<float4*>(out)[idx * 2 + 1] = r1;
}

extern "C" void kernel_launch(void* const* d_in, const int* in_sizes, int n_in,
                              void* d_out, int out_size, void* d_ws, size_t ws_size,
                              hipStream_t stream) {
    const float* x   = (const float*)d_in[0];
    const int*   ei  = (const int*)d_in[1];
    const float* ew  = (const float*)d_in[2];
    const float* W1  = (const float*)d_in[3];
    const float* g1  = (const float*)d_in[5];
    const float* be1 = (const float*)d_in[6];
    const float* W2  = (const float*)d_in[7];
    const float* g2  = (const float*)d_in[9];
    const float* be2 = (const float*)d_in[10];
    float* out = (float*)d_out;

    const int M = NNODES;
    const int E = in_sizes[2];
    const int* src = ei;
    const int* dst = ei + E;

    // workspace layout (~82 MB)
    unsigned short* hb   = (unsigned short*)d_ws;             // M*128 bf16 (25.6 MB)
    unsigned short* aggB = hb + (size_t)M * NHID;             // M*128 bf16 (25.6 MB)
    int2* bstage = (int2*)(aggB + (size_t)M * NHID);          // NB2*BCAP2 (14.5 MB)
    int2* s_iw   = bstage + (size_t)NB2 * BCAP2;              // NB2*BCAP2 (14.5 MB)
    int2* row_be = s_iw + (size_t)NB2 * BCAP2;                // N (800 KB)
    int* gcur    = (int*)(row_be + NNODES);                   // NB2*CURPAD (12.5 KB)
    unsigned short* Wt1b = (unsigned short*)(gcur + NB2 * CURPAD);  // 256*128 bf16
    unsigned short* Wt2b = Wt1b + DIN * NHID;                 // 128*128 bf16
    float* sums  = (float*)(Wt2b + NHID * NHID);              // 512 (both layers)

    const int gemm_grid = (M + 63) / 64;
    const int n8 = M * NHID / 8;
    const int app_grid = (n8 + 255) / 256;
    const int agg_grid = (M * 64 + 255) / 256;
    const int part_grid = (E + PH - 1) / PH;
    const int prep_tot = DIN * NHID + NHID * NHID + NB2 * CURPAD + 512;

    // ---- Prep, then fused GEMM1 || partition ----
    prep_kernel<<<(prep_tot + 255) / 256, 256, 0, stream>>>(W1, W2, Wt1b, Wt2b, gcur, sums);
    gemm1_part_kernel<<<gemm_grid + part_grid, 256, 0, stream>>>(
        x, Wt1b, hb, M, gemm_grid, src, dst, ew, gcur, bstage, E);
    csr_kernel<<<NB2 * 4, 512, 0, stream>>>(gcur, bstage, row_be, s_iw);

    // ---- Layer 1 ----
    aggregate_kernel<<<agg_grid, 256, 0, stream>>>(hb, row_be, s_iw, aggB, M);
    stats_kernel<<<1024, 256, 0, stream>>>(aggB, sums, M);

    // ---- Layer 2 (finalize1 + BN1 + ReLU fused into GEMM2's staging) ----
    mfma_gemm2<<<gemm_grid, 256, 0, stream>>>(aggB, Wt2b, sums, g1, be1, hb, M);
    aggregate_kernel<<<agg_grid, 256, 0, stream>>>(hb, row_be, s_iw, aggB, M);
    stats_kernel<<<1024, 256, 0, stream>>>(aggB, sums + 256, M);
    apply_kernel<<<app_grid, 256, 0, stream>>>(aggB, sums + 256, g2, be2, out, n8);
}

// Round 19
// 301.643 us; speedup vs baseline: 1.0037x; 1.0037x over previous
//
#include <hip/hip_runtime.h>
#include <hip/hip_bf16.h>

#define NNODES 100000
#define DIN    256
#define NHID   128
#define EPS    1e-5f
#define SHIFT  9
#define NB2    ((NNODES + 511) >> SHIFT)    // 196 buckets of 512 dst
#define BCAP2  9216                         // mean 8163 + ~11 sigma
#define CURPAD 16                           // global counters padded to 64B
#define PH     2048                         // edges per partition phase

typedef __attribute__((ext_vector_type(8))) short short8v;  // 8 x bf16
typedef __attribute__((ext_vector_type(4))) float f32x4;

static __device__ __forceinline__ unsigned short f2bf(float v) {
    __hip_bfloat16 b = __float2bfloat16(v);
    return *reinterpret_cast<unsigned short*>(&b);
}
static __device__ __forceinline__ float bfhi2f(unsigned int u) {
    union { unsigned int i; float f; } x; x.i = u & 0xFFFF0000u; return x.f;
}
static __device__ __forceinline__ float bflo2f(unsigned int u) {
    union { unsigned int i; float f; } x; x.i = u << 16; return x.f;
}

// ---------------- Prep: W transposes + counter/stat zeroing ----------------
__global__ __launch_bounds__(256) void prep_kernel(const float* __restrict__ W1,
                                                   const float* __restrict__ W2,
                                                   unsigned short* __restrict__ Wt1,
                                                   unsigned short* __restrict__ Wt2,
                                                   int* __restrict__ gcur,
                                                   float* __restrict__ sums) {
    int i = blockIdx.x * 256 + threadIdx.x;
    if (i < DIN * NHID) {
        const int k = i >> 7, c = i & 127;
        Wt1[c * DIN + k] = f2bf(W1[i]);
        return;
    }
    i -= DIN * NHID;
    if (i < NHID * NHID) {
        const int k = i >> 7, c = i & 127;
        Wt2[c * NHID + k] = f2bf(W2[i]);
        return;
    }
    i -= NHID * NHID;
    if (i < NB2 * CURPAD) { gcur[i] = 0; return; }
    i -= NB2 * CURPAD;
    if (i < 512) sums[i] = 0.f;
}

// ---------------- Fused: GEMM1 (blocks < ngemm) || edge partition (rest) ----------------
__global__ __launch_bounds__(256) void gemm1_part_kernel(
    const float* __restrict__ Af, const unsigned short* __restrict__ Wtb,
    unsigned short* __restrict__ C, int M, int ngemm,
    const int* __restrict__ src, const int* __restrict__ dst,
    const float* __restrict__ w, int* __restrict__ gcur,
    int2* __restrict__ bstage, int E) {
    struct GemmS { unsigned short As[2][64 * 40]; };
    struct PartS {
        int2 staged[PH];
        int hist[NB2], scn[NB2], cur[NB2], gbase[NB2];
        int pscan[256];
        unsigned char aux[PH];
    };
    __shared__ union { GemmS g; PartS p; } sm;

    const int t = threadIdx.x;
    if (blockIdx.x < ngemm) {
        constexpr int K = DIN;
        constexpr int NS = K / 32;
        constexpr int PADB = 40;
        const int wid = t >> 6;
        const int lane = t & 63;
        const int wr = wid >> 1, wc = wid & 1;
        const int l15 = lane & 15, g = lane >> 4;
        const int R0 = blockIdx.x * 64;
        const int RW = R0 + wr * 32;
        const int srow = t >> 2;
        const int scol = (t & 3) * 8;

        f32x4 acc[2][4] = {};

        auto STAGE = [&](int s, int buf) {
            const int k0 = s * 32;
            int grow = R0 + srow;
            grow = grow < M ? grow : M - 1;
            const float* p = Af + (size_t)grow * K + k0 + scol;
            const float4 v0 = *reinterpret_cast<const float4*>(p);
            const float4 v1 = *reinterpret_cast<const float4*>(p + 4);
            unsigned short bv[8];
            bv[0] = f2bf(v0.x); bv[1] = f2bf(v0.y); bv[2] = f2bf(v0.z); bv[3] = f2bf(v0.w);
            bv[4] = f2bf(v1.x); bv[5] = f2bf(v1.y); bv[6] = f2bf(v1.z); bv[7] = f2bf(v1.w);
            *reinterpret_cast<uint4*>(&sm.g.As[buf][srow * PADB + scol]) =
                *reinterpret_cast<const uint4*>(bv);
        };

        STAGE(0, 0);
        __syncthreads();

        for (int s = 0; s < NS; ++s) {
            if (s + 1 < NS) STAGE(s + 1, (s + 1) & 1);
            const unsigned short* ab = sm.g.As[s & 1];
            short8v b[4];
#pragma unroll
            for (int n = 0; n < 4; ++n) {
                const int col = wc * 64 + n * 16 + l15;
                b[n] = *reinterpret_cast<const short8v*>(&Wtb[(size_t)col * K + s * 32 + g * 8]);
            }
            short8v a[2];
#pragma unroll
            for (int m = 0; m < 2; ++m) {
                const int row = wr * 32 + m * 16 + l15;
                a[m] = *reinterpret_cast<const short8v*>(&ab[row * PADB + g * 8]);
            }
#pragma unroll
            for (int m = 0; m < 2; ++m)
#pragma unroll
                for (int n = 0; n < 4; ++n)
                    acc[m][n] = __builtin_amdgcn_mfma_f32_16x16x32_bf16(a[m], b[n], acc[m][n], 0, 0, 0);
            __syncthreads();
        }

#pragma unroll
        for (int m = 0; m < 2; ++m) {
#pragma unroll
            for (int q = 0; q < 4; ++q) {
                const int row = RW + m * 16 + g * 4 + q;
                if (row < M) {
                    unsigned short* cp = C + (size_t)row * NHID + wc * 64 + l15;
#pragma unroll
                    for (int n = 0; n < 4; ++n)
                        cp[n * 16] = f2bf(acc[m][n][q]);
                }
            }
        }
    } else {
        // ---- partition path ----
        const int c = blockIdx.x - ngemm;
        const int e0 = c * PH;
        if (e0 >= E) return;
        const int cnt = min(PH, E - e0);
        for (int i = t; i < NB2; i += 256) sm.p.hist[i] = 0;
        __syncthreads();

        int2 pay[8];
        int bk[8];
#pragma unroll
        for (int j = 0; j < 8; ++j) {
            const int i = j * 256 + t;
            bk[j] = -1;
            if (i < cnt) {
                const int e = e0 + i;
                const int d = dst[e];
                bk[j] = d >> SHIFT;
                pay[j].x = src[e] | ((d & 511) << 17);
                pay[j].y = __float_as_int(w[e]);
                atomicAdd(&sm.p.hist[bk[j]], 1);
            }
        }
        __syncthreads();

        sm.p.pscan[t] = (t < NB2) ? sm.p.hist[t] : 0;
        __syncthreads();
        for (int off = 1; off < 256; off <<= 1) {
            const int v = (t >= off) ? sm.p.pscan[t - off] : 0;
            __syncthreads();
            sm.p.pscan[t] += v;
            __syncthreads();
        }
        if (t < NB2) {
            const int ex = sm.p.pscan[t] - sm.p.hist[t];
            sm.p.scn[t] = ex;
            sm.p.cur[t] = ex;
        }
        __syncthreads();

#pragma unroll
        for (int j = 0; j < 8; ++j) {
            if (bk[j] >= 0) {
                const int p = atomicAdd(&sm.p.cur[bk[j]], 1);
                sm.p.staged[p] = pay[j];
                sm.p.aux[p] = (unsigned char)bk[j];
            }
        }
        if (t < NB2 && sm.p.hist[t] > 0)
            sm.p.gbase[t] = atomicAdd(&gcur[t * CURPAD], sm.p.hist[t]);
        __syncthreads();

        for (int i = t; i < cnt; i += 256) {
            const int b = sm.p.aux[i];
            const int p = sm.p.gbase[b] + (i - sm.p.scn[b]);
            if (p < BCAP2) bstage[(size_t)b * BCAP2 + p] = sm.p.staged[i];
        }
    }
}

// ---------------- csrA: partial hist per quarter (784 blocks) ----------------
__global__ __launch_bounds__(512) void csrA_kernel(const int* __restrict__ gcur,
                                                   const int2* __restrict__ bstage,
                                                   int* __restrict__ phist) {
    const int b = blockIdx.x >> 2;
    const int k = blockIdx.x & 3;
    const int t = threadIdx.x;
    int cnt = gcur[b * CURPAD];
    if (cnt > BCAP2) cnt = BCAP2;
    const int sbase = b * BCAP2;
    const int h0 = (cnt * k) >> 2;
    const int h1 = (cnt * (k + 1)) >> 2;

    __shared__ int hist[512];
    hist[t] = 0;
    __syncthreads();
    for (int i = h0 + t; i < h1; i += 512)
        atomicAdd(&hist[(bstage[sbase + i].x >> 17) & 511], 1);
    __syncthreads();
    phist[(blockIdx.x << 9) + t] = hist[t];
}

// ---------------- csrB: scan partials + scatter own quarter (784 blocks) ----------------
__global__ __launch_bounds__(512) void csrB_kernel(const int* __restrict__ gcur,
                                                   const int2* __restrict__ bstage,
                                                   const int* __restrict__ phist,
                                                   int2* __restrict__ row_be,
                                                   int2* __restrict__ s_iw) {
    const int b = blockIdx.x >> 2;
    const int k = blockIdx.x & 3;
    const int t = threadIdx.x;
    int cnt = gcur[b * CURPAD];
    if (cnt > BCAP2) cnt = BCAP2;
    const int sbase = b * BCAP2;
    const int h0 = (cnt * k) >> 2;
    const int h1 = (cnt * (k + 1)) >> 2;

    __shared__ int cur[512], part[512];
    const int* ph = phist + ((size_t)(b * 4) << 9);
    const int p0 = ph[t], p1 = ph[512 + t], p2 = ph[1024 + t], p3 = ph[1536 + t];
    const int tot = p0 + p1 + p2 + p3;
    part[t] = tot;
    __syncthreads();
    for (int off = 1; off < 512; off <<= 1) {
        const int v = (t >= off) ? part[t - off] : 0;
        __syncthreads();
        part[t] += v;
        __syncthreads();
    }
    const int excl = part[t] - tot;
    int mypre = 0;
    if (k > 0) mypre += p0;
    if (k > 1) mypre += p1;
    if (k > 2) mypre += p2;
    cur[t] = excl + mypre;
    if (k == 0) {
        const int d = (b << SHIFT) + t;
        if (d < NNODES) {
            int2 be;
            be.x = sbase + excl;
            be.y = sbase + excl + tot;
            row_be[d] = be;
        }
    }
    __syncthreads();

    for (int i = h0 + t; i < h1; i += 512) {
        const int2 e = bstage[sbase + i];
        const int l = (e.x >> 17) & 511;
        const int p = atomicAdd(&cur[l], 1);
        int2 o;
        o.x = e.x & 0x1FFFF;
        o.y = e.y;
        s_iw[sbase + p] = o;
    }
}

// ---------------- Aggregate: 16-lane edge groups, uint4 loads; bf16 output ----------------
__global__ __launch_bounds__(256) void aggregate_kernel(const unsigned short* __restrict__ hb,
                                                        const int2* __restrict__ row_be,
                                                        const int2* __restrict__ s_iw,
                                                        unsigned short* __restrict__ outB, int n) {
    const int wid = (blockIdx.x * 256 + threadIdx.x) >> 6;
    if (wid >= n) return;
    const int lane = threadIdx.x & 63;
    const int grp = lane >> 4;     // edge slot 0..3
    const int l16 = lane & 15;     // col group: cols l16*8 .. +7
    const int2 be = row_be[wid];
    const int end = be.y;

    float acc[8] = {};
    int j = be.x + grp;
    for (; j + 4 < end; j += 8) {
        const int2 e0 = s_iw[j];
        const int2 e1 = s_iw[j + 4];
        const uint4 v0 = *reinterpret_cast<const uint4*>(hb + (size_t)e0.x * NHID + l16 * 8);
        const uint4 v1 = *reinterpret_cast<const uint4*>(hb + (size_t)e1.x * NHID + l16 * 8);
        const float w0 = __int_as_float(e0.y);
        const float w1 = __int_as_float(e1.y);
        acc[0] = fmaf(w0, bflo2f(v0.x), acc[0]); acc[1] = fmaf(w0, bfhi2f(v0.x), acc[1]);
        acc[2] = fmaf(w0, bflo2f(v0.y), acc[2]); acc[3] = fmaf(w0, bfhi2f(v0.y), acc[3]);
        acc[4] = fmaf(w0, bflo2f(v0.z), acc[4]); acc[5] = fmaf(w0, bfhi2f(v0.z), acc[5]);
        acc[6] = fmaf(w0, bflo2f(v0.w), acc[6]); acc[7] = fmaf(w0, bfhi2f(v0.w), acc[7]);
        acc[0] = fmaf(w1, bflo2f(v1.x), acc[0]); acc[1] = fmaf(w1, bfhi2f(v1.x), acc[1]);
        acc[2] = fmaf(w1, bflo2f(v1.y), acc[2]); acc[3] = fmaf(w1, bfhi2f(v1.y), acc[3]);
        acc[4] = fmaf(w1, bflo2f(v1.z), acc[4]); acc[5] = fmaf(w1, bfhi2f(v1.z), acc[5]);
        acc[6] = fmaf(w1, bflo2f(v1.w), acc[6]); acc[7] = fmaf(w1, bfhi2f(v1.w), acc[7]);
    }
    if (j < end) {
        const int2 e0 = s_iw[j];
        const uint4 v0 = *reinterpret_cast<const uint4*>(hb + (size_t)e0.x * NHID + l16 * 8);
        const float w0 = __int_as_float(e0.y);
        acc[0] = fmaf(w0, bflo2f(v0.x), acc[0]); acc[1] = fmaf(w0, bfhi2f(v0.x), acc[1]);
        acc[2] = fmaf(w0, bflo2f(v0.y), acc[2]); acc[3] = fmaf(w0, bfhi2f(v0.y), acc[3]);
        acc[4] = fmaf(w0, bflo2f(v0.z), acc[4]); acc[5] = fmaf(w0, bfhi2f(v0.z), acc[5]);
        acc[6] = fmaf(w0, bflo2f(v0.w), acc[6]); acc[7] = fmaf(w0, bfhi2f(v0.w), acc[7]);
    }
#pragma unroll
    for (int k = 0; k < 8; ++k) {
        acc[k] += __shfl_xor(acc[k], 16, 64);
        acc[k] += __shfl_xor(acc[k], 32, 64);
    }
    if (grp == 0) {
        unsigned short bv[8];
#pragma unroll
        for (int k = 0; k < 8; ++k) bv[k] = f2bf(acc[k]);
        *reinterpret_cast<uint4*>(outB + (size_t)wid * NHID + l16 * 8) =
            *reinterpret_cast<const uint4*>(bv);
    }
}

// ---------------- BN stats over bf16 buffer ----------------
__global__ __launch_bounds__(256) void stats_kernel(const unsigned short* __restrict__ h,
                                                    float* __restrict__ sums, int nrows) {
    const int t = threadIdx.x;
    const int cp = t & 63;
    const int rg = t >> 6;
    float s0 = 0.f, s1 = 0.f, q0 = 0.f, q1 = 0.f;
    for (int r = blockIdx.x * 4 + rg; r < nrows; r += gridDim.x * 4) {
        const unsigned int v = *reinterpret_cast<const unsigned int*>(h + (size_t)r * NHID + cp * 2);
        const float a = bflo2f(v), b = bfhi2f(v);
        s0 += a; q0 = fmaf(a, a, q0);
        s1 += b; q1 = fmaf(b, b, q1);
    }
    __shared__ float ls[4][128], lq[4][128];
    ls[rg][cp * 2] = s0; ls[rg][cp * 2 + 1] = s1;
    lq[rg][cp * 2] = q0; lq[rg][cp * 2 + 1] = q1;
    __syncthreads();
    if (t < 128) {
        atomicAdd(&sums[t], ls[0][t] + ls[1][t] + ls[2][t] + ls[3][t]);
    } else {
        const int c = t - 128;
        atomicAdd(&sums[128 + c], lq[0][c] + lq[1][c] + lq[2][c] + lq[3][c]);
    }
}

// ---------------- GEMM2: bf16 A + fused finalize(BN1) + BN+ReLU at staging ----------------
__global__ __launch_bounds__(256) void mfma_gemm2(const unsigned short* __restrict__ Ab,
                                                  const unsigned short* __restrict__ Wtb,
                                                  const float* __restrict__ sums,
                                                  const float* __restrict__ gamma,
                                                  const float* __restrict__ beta,
                                                  unsigned short* __restrict__ C, int M) {
    constexpr int K = NHID;
    constexpr int NS = K / 32;
    constexpr int PADB = 40;
    __shared__ unsigned short As[2][64 * PADB];
    __shared__ float ssl[256];

    const int t = threadIdx.x;
    if (t < 128) {
        const float invN = 1.0f / (float)NNODES;
        const float mean = sums[t] * invN;
        const float var = sums[128 + t] * invN - mean * mean;
        const float scale = gamma[t] * rsqrtf(var + EPS);
        ssl[t] = scale;
        ssl[128 + t] = beta[t] - mean * scale;
    }
    __syncthreads();

    const int wid = t >> 6;
    const int lane = t & 63;
    const int wr = wid >> 1, wc = wid & 1;
    const int l15 = lane & 15, g = lane >> 4;
    const int R0 = blockIdx.x * 64;
    const int RW = R0 + wr * 32;
    const int srow = t >> 2;
    const int scol = (t & 3) * 8;

    f32x4 acc[2][4] = {};

    auto STAGE = [&](int s, int buf) {
        const int k0 = s * 32;
        int grow = R0 + srow;
        grow = grow < M ? grow : M - 1;
        const uint4 v = *reinterpret_cast<const uint4*>(Ab + (size_t)grow * K + k0 + scol);
        const float f[8] = {bflo2f(v.x), bfhi2f(v.x), bflo2f(v.y), bfhi2f(v.y),
                            bflo2f(v.z), bfhi2f(v.z), bflo2f(v.w), bfhi2f(v.w)};
        const int c0 = k0 + scol;
        unsigned short bv[8];
#pragma unroll
        for (int j = 0; j < 8; ++j)
            bv[j] = f2bf(fmaxf(fmaf(f[j], ssl[c0 + j], ssl[128 + c0 + j]), 0.f));
        *reinterpret_cast<uint4*>(&As[buf][srow * PADB + scol]) =
            *reinterpret_cast<const uint4*>(bv);
    };

    STAGE(0, 0);
    __syncthreads();

    for (int s = 0; s < NS; ++s) {
        if (s + 1 < NS) STAGE(s + 1, (s + 1) & 1);
        const unsigned short* ab = As[s & 1];
        short8v b[4];
#pragma unroll
        for (int n = 0; n < 4; ++n) {
            const int col = wc * 64 + n * 16 + l15;
            b[n] = *reinterpret_cast<const short8v*>(&Wtb[(size_t)col * K + s * 32 + g * 8]);
        }
        short8v a[2];
#pragma unroll
        for (int m = 0; m < 2; ++m) {
            const int row = wr * 32 + m * 16 + l15;
            a[m] = *reinterpret_cast<const short8v*>(&ab[row * PADB + g * 8]);
        }
#pragma unroll
        for (int m = 0; m < 2; ++m)
#pragma unroll
            for (int n = 0; n < 4; ++n)
                acc[m][n] = __builtin_amdgcn_mfma_f32_16x16x32_bf16(a[m], b[n], acc[m][n], 0, 0, 0);
        __syncthreads();
    }

#pragma unroll
    for (int m = 0; m < 2; ++m) {
#pragma unroll
        for (int q = 0; q < 4; ++q) {
            const int row = RW + m * 16 + g * 4 + q;
            if (row < M) {
                unsigned short* cp = C + (size_t)row * NHID + wc * 64 + l15;
#pragma unroll
                for (int n = 0; n < 4; ++n)
                    cp[n * 16] = f2bf(acc[m][n][q]);
            }
        }
    }
}

// ---------------- Final apply: fused finalize(BN2) + BN+ReLU, bf16 in / fp32 out ----------------
__global__ __launch_bounds__(256) void apply_kernel(const unsigned short* __restrict__ aggB,
                                                    const float* __restrict__ sums,
                                                    const float* __restrict__ gamma,
                                                    const float* __restrict__ beta,
                                                    float* __restrict__ out, int n8) {
    __shared__ float ss[256];
    const int t = threadIdx.x;
    if (t < 128) {
        const float invN = 1.0f / (float)NNODES;
        const float mean = sums[t] * invN;
        const float var = sums[128 + t] * invN - mean * mean;
        const float scale = gamma[t] * rsqrtf(var + EPS);
        ss[t] = scale;
        ss[128 + t] = beta[t] - mean * scale;
    }
    __syncthreads();
    const int idx = blockIdx.x * 256 + t;
    if (idx >= n8) return;
    const int c0 = (idx & 15) * 8;
    const uint4 v = reinterpret_cast<const uint4*>(aggB)[idx];
    const float f[8] = {bflo2f(v.x), bfhi2f(v.x), bflo2f(v.y), bfhi2f(v.y),
                        bflo2f(v.z), bfhi2f(v.z), bflo2f(v.w), bfhi2f(v.w)};
    float4 r0, r1;
    r0.x = fmaxf(fmaf(f[0], ss[c0],     ss[128 + c0]),     0.f);
    r0.y = fmaxf(fmaf(f[1], ss[c0 + 1], ss[128 + c0 + 1]), 0.f);
    r0.z = fmaxf(fmaf(f[2], ss[c0 + 2], ss[128 + c0 + 2]), 0.f);
    r0.w = fmaxf(fmaf(f[3], ss[c0 + 3], ss[128 + c0 + 3]), 0.f);
    r1.x = fmaxf(fmaf(f[4], ss[c0 + 4], ss[128 + c0 + 4]), 0.f);
    r1.y = fmaxf(fmaf(f[5], ss[c0 + 5], ss[128 + c0 + 5]), 0.f);
    r1.z = fmaxf(fmaf(f[6], ss[c0 + 6], ss[128 + c0 + 6]), 0.f);
    r1.w = fmaxf(fmaf(f[7], ss[c0 + 7], ss[128 + c0 + 7]), 0.f);
    reinterpret_cast<float4*>(out)[idx * 2] = r0;
    reinterpret_cast<float4*>(out)[idx * 2 + 1] = r1;
}

extern "C" void kernel_launch(void* const* d_in, const int* in_sizes, int n_in,
                              void* d_out, int out_size, void* d_ws, size_t ws_size,
                              hipStream_t stream) {
    const float* x   = (const float*)d_in[0];
    const int*   ei  = (const int*)d_in[1];
    const float* ew  = (const float*)d_in[2];
    const float* W1  = (const float*)d_in[3];
    const float* g1  = (const float*)d_in[5];
    const float* be1 = (const float*)d_in[6];
    const float* W2  = (const float*)d_in[7];
    const float* g2  = (const float*)d_in[9];
    const float* be2 = (const float*)d_in[10];
    float* out = (float*)d_out;

    const int M = NNODES;
    const int E = in_sizes[2];
    const int* src = ei;
    const int* dst = ei + E;

    // workspace layout (~84 MB)
    unsigned short* hb   = (unsigned short*)d_ws;             // M*128 bf16 (25.6 MB)
    unsigned short* aggB = hb + (size_t)M * NHID;             // M*128 bf16 (25.6 MB)
    int2* bstage = (int2*)(aggB + (size_t)M * NHID);          // NB2*BCAP2 (14.5 MB)
    int2* s_iw   = bstage + (size_t)NB2 * BCAP2;              // NB2*BCAP2 (14.5 MB)
    int2* row_be = s_iw + (size_t)NB2 * BCAP2;                // N (800 KB)
    int* gcur    = (int*)(row_be + NNODES);                   // NB2*CURPAD (12.5 KB)
    int* phist   = gcur + NB2 * CURPAD;                       // NB2*4*512 (1.6 MB)
    unsigned short* Wt1b = (unsigned short*)(phist + NB2 * 4 * 512);  // 256*128 bf16
    unsigned short* Wt2b = Wt1b + DIN * NHID;                 // 128*128 bf16
    float* sums  = (float*)(Wt2b + NHID * NHID);              // 512 (both layers)

    const int gemm_grid = (M + 63) / 64;
    const int n8 = M * NHID / 8;
    const int app_grid = (n8 + 255) / 256;
    const int agg_grid = (M * 64 + 255) / 256;
    const int part_grid = (E + PH - 1) / PH;
    const int prep_tot = DIN * NHID + NHID * NHID + NB2 * CURPAD + 512;

    // ---- Prep, then fused GEMM1 || partition, then 2-phase parallel CSR ----
    prep_kernel<<<(prep_tot + 255) / 256, 256, 0, stream>>>(W1, W2, Wt1b, Wt2b, gcur, sums);
    gemm1_part_kernel<<<gemm_grid + part_grid, 256, 0, stream>>>(
        x, Wt1b, hb, M, gemm_grid, src, dst, ew, gcur, bstage, E);
    csrA_kernel<<<NB2 * 4, 512, 0, stream>>>(gcur, bstage, phist);
    csrB_kernel<<<NB2 * 4, 512, 0, stream>>>(gcur, bstage, phist, row_be, s_iw);

    // ---- Layer 1 ----
    aggregate_kernel<<<agg_grid, 256, 0, stream>>>(hb, row_be, s_iw, aggB, M);
    stats_kernel<<<1024, 256, 0, stream>>>(aggB, sums, M);

    // ---- Layer 2 (finalize1 + BN1 + ReLU fused into GEMM2's staging) ----
    mfma_gemm2<<<gemm_grid, 256, 0, stream>>>(aggB, Wt2b, sums, g1, be1, hb, M);
    aggregate_kernel<<<agg_grid, 256, 0, stream>>>(hb, row_be, s_iw, aggB, M);
    stats_kernel<<<1024, 256, 0, stream>>>(aggB, sums + 256, M);
    apply_kernel<<<app_grid, 256, 0, stream>>>(aggB, sums + 256, g2, be2, out, n8);
}

// Round 20
// 293.760 us; speedup vs baseline: 1.0306x; 1.0268x over previous
//
#include <hip/hip_runtime.h>
#include <hip/hip_bf16.h>

#define NNODES 100000
#define DIN    256
#define NHID   128
#define EPS    1e-5f
#define SHIFT  9
#define NB2    ((NNODES + 511) >> SHIFT)    // 196 buckets of 512 dst
#define BCAP2  9216                         // mean 8163 + ~11 sigma
#define CURPAD 16                           // global counters padded to 64B
#define PH     2048                         // edges per partition phase

typedef __attribute__((ext_vector_type(8))) short short8v;  // 8 x bf16
typedef __attribute__((ext_vector_type(4))) float f32x4;

static __device__ __forceinline__ unsigned short f2bf(float v) {
    __hip_bfloat16 b = __float2bfloat16(v);
    return *reinterpret_cast<unsigned short*>(&b);
}
static __device__ __forceinline__ float bfhi2f(unsigned int u) {
    union { unsigned int i; float f; } x; x.i = u & 0xFFFF0000u; return x.f;
}
static __device__ __forceinline__ float bflo2f(unsigned int u) {
    union { unsigned int i; float f; } x; x.i = u << 16; return x.f;
}

// ---------------- Prep: W transposes + counter/stat zeroing ----------------
__global__ __launch_bounds__(256) void prep_kernel(const float* __restrict__ W1,
                                                   const float* __restrict__ W2,
                                                   unsigned short* __restrict__ Wt1,
                                                   unsigned short* __restrict__ Wt2,
                                                   int* __restrict__ gcur,
                                                   float* __restrict__ sums) {
    int i = blockIdx.x * 256 + threadIdx.x;
    if (i < DIN * NHID) {
        const int k = i >> 7, c = i & 127;
        Wt1[c * DIN + k] = f2bf(W1[i]);
        return;
    }
    i -= DIN * NHID;
    if (i < NHID * NHID) {
        const int k = i >> 7, c = i & 127;
        Wt2[c * NHID + k] = f2bf(W2[i]);
        return;
    }
    i -= NHID * NHID;
    if (i < NB2 * CURPAD) { gcur[i] = 0; return; }
    i -= NB2 * CURPAD;
    if (i < 512) sums[i] = 0.f;
}

// ---------------- Fused: GEMM1 (blocks < ngemm) || edge partition (rest) ----------------
// GEMM: BM=64 tile, 2x2 waves of 32r x 64c, double-buffered LDS A (fp32 x -> bf16).
// Part: per-2048-edge chunk LDS hist/scan/scatter -> coalesced bucket writes.
__global__ __launch_bounds__(256) void gemm1_part_kernel(
    const float* __restrict__ Af, const unsigned short* __restrict__ Wtb,
    unsigned short* __restrict__ C, int M, int ngemm,
    const int* __restrict__ src, const int* __restrict__ dst,
    const float* __restrict__ w, int* __restrict__ gcur,
    int2* __restrict__ bstage, int E) {
    struct GemmS { unsigned short As[2][64 * 40]; };
    struct PartS {
        int2 staged[PH];
        int hist[NB2], scn[NB2], cur[NB2], gbase[NB2];
        int pscan[256];
        unsigned char aux[PH];
    };
    __shared__ union { GemmS g; PartS p; } sm;

    const int t = threadIdx.x;
    if (blockIdx.x < ngemm) {
        constexpr int K = DIN;
        constexpr int NS = K / 32;
        constexpr int PADB = 40;
        const int wid = t >> 6;
        const int lane = t & 63;
        const int wr = wid >> 1, wc = wid & 1;
        const int l15 = lane & 15, g = lane >> 4;
        const int R0 = blockIdx.x * 64;
        const int RW = R0 + wr * 32;
        const int srow = t >> 2;
        const int scol = (t & 3) * 8;

        f32x4 acc[2][4] = {};

        auto STAGE = [&](int s, int buf) {
            const int k0 = s * 32;
            int grow = R0 + srow;
            grow = grow < M ? grow : M - 1;
            const float* p = Af + (size_t)grow * K + k0 + scol;
            const float4 v0 = *reinterpret_cast<const float4*>(p);
            const float4 v1 = *reinterpret_cast<const float4*>(p + 4);
            unsigned short bv[8];
            bv[0] = f2bf(v0.x); bv[1] = f2bf(v0.y); bv[2] = f2bf(v0.z); bv[3] = f2bf(v0.w);
            bv[4] = f2bf(v1.x); bv[5] = f2bf(v1.y); bv[6] = f2bf(v1.z); bv[7] = f2bf(v1.w);
            *reinterpret_cast<uint4*>(&sm.g.As[buf][srow * PADB + scol]) =
                *reinterpret_cast<const uint4*>(bv);
        };

        STAGE(0, 0);
        __syncthreads();

        for (int s = 0; s < NS; ++s) {
            if (s + 1 < NS) STAGE(s + 1, (s + 1) & 1);
            const unsigned short* ab = sm.g.As[s & 1];
            short8v b[4];
#pragma unroll
            for (int n = 0; n < 4; ++n) {
                const int col = wc * 64 + n * 16 + l15;
                b[n] = *reinterpret_cast<const short8v*>(&Wtb[(size_t)col * K + s * 32 + g * 8]);
            }
            short8v a[2];
#pragma unroll
            for (int m = 0; m < 2; ++m) {
                const int row = wr * 32 + m * 16 + l15;
                a[m] = *reinterpret_cast<const short8v*>(&ab[row * PADB + g * 8]);
            }
#pragma unroll
            for (int m = 0; m < 2; ++m)
#pragma unroll
                for (int n = 0; n < 4; ++n)
                    acc[m][n] = __builtin_amdgcn_mfma_f32_16x16x32_bf16(a[m], b[n], acc[m][n], 0, 0, 0);
            __syncthreads();
        }

#pragma unroll
        for (int m = 0; m < 2; ++m) {
#pragma unroll
            for (int q = 0; q < 4; ++q) {
                const int row = RW + m * 16 + g * 4 + q;
                if (row < M) {
                    unsigned short* cp = C + (size_t)row * NHID + wc * 64 + l15;
#pragma unroll
                    for (int n = 0; n < 4; ++n)
                        cp[n * 16] = f2bf(acc[m][n][q]);
                }
            }
        }
    } else {
        // ---- partition path ----
        const int c = blockIdx.x - ngemm;
        const int e0 = c * PH;
        if (e0 >= E) return;
        const int cnt = min(PH, E - e0);
        for (int i = t; i < NB2; i += 256) sm.p.hist[i] = 0;
        __syncthreads();

        int2 pay[8];
        int bk[8];
#pragma unroll
        for (int j = 0; j < 8; ++j) {
            const int i = j * 256 + t;
            bk[j] = -1;
            if (i < cnt) {
                const int e = e0 + i;
                const int d = dst[e];
                bk[j] = d >> SHIFT;
                pay[j].x = src[e] | ((d & 511) << 17);
                pay[j].y = __float_as_int(w[e]);
                atomicAdd(&sm.p.hist[bk[j]], 1);
            }
        }
        __syncthreads();

        sm.p.pscan[t] = (t < NB2) ? sm.p.hist[t] : 0;
        __syncthreads();
        for (int off = 1; off < 256; off <<= 1) {
            const int v = (t >= off) ? sm.p.pscan[t - off] : 0;
            __syncthreads();
            sm.p.pscan[t] += v;
            __syncthreads();
        }
        if (t < NB2) {
            const int ex = sm.p.pscan[t] - sm.p.hist[t];
            sm.p.scn[t] = ex;
            sm.p.cur[t] = ex;
        }
        __syncthreads();

#pragma unroll
        for (int j = 0; j < 8; ++j) {
            if (bk[j] >= 0) {
                const int p = atomicAdd(&sm.p.cur[bk[j]], 1);
                sm.p.staged[p] = pay[j];
                sm.p.aux[p] = (unsigned char)bk[j];
            }
        }
        if (t < NB2 && sm.p.hist[t] > 0)
            sm.p.gbase[t] = atomicAdd(&gcur[t * CURPAD], sm.p.hist[t]);
        __syncthreads();

        for (int i = t; i < cnt; i += 256) {
            const int b = sm.p.aux[i];
            const int p = sm.p.gbase[b] + (i - sm.p.scn[b]);
            if (p < BCAP2) bstage[(size_t)b * BCAP2 + p] = sm.p.staged[i];
        }
    }
}

// ---------------- Pass B: per-bucket exact CSR (512 bins, 512 threads) ----------------
__global__ __launch_bounds__(512) void csr_kernel(const int* __restrict__ gcur,
                                                  const int2* __restrict__ bstage,
                                                  int2* __restrict__ row_be,
                                                  int2* __restrict__ s_iw) {
    const int b = blockIdx.x;
    const int t = threadIdx.x;
    int cnt = gcur[b * CURPAD];
    if (cnt > BCAP2) cnt = BCAP2;
    const int sbase = b * BCAP2;

    __shared__ int hist[512], cur[512];
    __shared__ int part[512];
    hist[t] = 0;
    __syncthreads();
    for (int i = t; i < cnt; i += 512)
        atomicAdd(&hist[(bstage[sbase + i].x >> 17) & 511], 1);
    __syncthreads();

    part[t] = hist[t];
    __syncthreads();
    for (int off = 1; off < 512; off <<= 1) {
        const int v = (t >= off) ? part[t - off] : 0;
        __syncthreads();
        part[t] += v;
        __syncthreads();
    }
    const int excl = part[t] - hist[t];
    cur[t] = excl;
    const int d = (b << SHIFT) + t;
    if (d < NNODES) {
        int2 be;
        be.x = sbase + excl;
        be.y = sbase + part[t];
        row_be[d] = be;
    }
    __syncthreads();

    for (int i = t; i < cnt; i += 512) {
        const int2 e = bstage[sbase + i];
        const int l = (e.x >> 17) & 511;
        const int p = atomicAdd(&cur[l], 1);
        int2 o;
        o.x = e.x & 0x1FFFF;
        o.y = e.y;
        s_iw[sbase + p] = o;
    }
}

// ---------------- Aggregate: 16-lane edge groups, uint4 loads; bf16 output ----------------
__global__ __launch_bounds__(256) void aggregate_kernel(const unsigned short* __restrict__ hb,
                                                        const int2* __restrict__ row_be,
                                                        const int2* __restrict__ s_iw,
                                                        unsigned short* __restrict__ outB, int n) {
    const int wid = (blockIdx.x * 256 + threadIdx.x) >> 6;
    if (wid >= n) return;
    const int lane = threadIdx.x & 63;
    const int grp = lane >> 4;     // edge slot 0..3
    const int l16 = lane & 15;     // col group: cols l16*8 .. +7
    const int2 be = row_be[wid];
    const int end = be.y;

    float acc[8] = {};
    int j = be.x + grp;
    for (; j + 4 < end; j += 8) {
        const int2 e0 = s_iw[j];
        const int2 e1 = s_iw[j + 4];
        const uint4 v0 = *reinterpret_cast<const uint4*>(hb + (size_t)e0.x * NHID + l16 * 8);
        const uint4 v1 = *reinterpret_cast<const uint4*>(hb + (size_t)e1.x * NHID + l16 * 8);
        const float w0 = __int_as_float(e0.y);
        const float w1 = __int_as_float(e1.y);
        acc[0] = fmaf(w0, bflo2f(v0.x), acc[0]); acc[1] = fmaf(w0, bfhi2f(v0.x), acc[1]);
        acc[2] = fmaf(w0, bflo2f(v0.y), acc[2]); acc[3] = fmaf(w0, bfhi2f(v0.y), acc[3]);
        acc[4] = fmaf(w0, bflo2f(v0.z), acc[4]); acc[5] = fmaf(w0, bfhi2f(v0.z), acc[5]);
        acc[6] = fmaf(w0, bflo2f(v0.w), acc[6]); acc[7] = fmaf(w0, bfhi2f(v0.w), acc[7]);
        acc[0] = fmaf(w1, bflo2f(v1.x), acc[0]); acc[1] = fmaf(w1, bfhi2f(v1.x), acc[1]);
        acc[2] = fmaf(w1, bflo2f(v1.y), acc[2]); acc[3] = fmaf(w1, bfhi2f(v1.y), acc[3]);
        acc[4] = fmaf(w1, bflo2f(v1.z), acc[4]); acc[5] = fmaf(w1, bfhi2f(v1.z), acc[5]);
        acc[6] = fmaf(w1, bflo2f(v1.w), acc[6]); acc[7] = fmaf(w1, bfhi2f(v1.w), acc[7]);
    }
    if (j < end) {
        const int2 e0 = s_iw[j];
        const uint4 v0 = *reinterpret_cast<const uint4*>(hb + (size_t)e0.x * NHID + l16 * 8);
        const float w0 = __int_as_float(e0.y);
        acc[0] = fmaf(w0, bflo2f(v0.x), acc[0]); acc[1] = fmaf(w0, bfhi2f(v0.x), acc[1]);
        acc[2] = fmaf(w0, bflo2f(v0.y), acc[2]); acc[3] = fmaf(w0, bfhi2f(v0.y), acc[3]);
        acc[4] = fmaf(w0, bflo2f(v0.z), acc[4]); acc[5] = fmaf(w0, bfhi2f(v0.z), acc[5]);
        acc[6] = fmaf(w0, bflo2f(v0.w), acc[6]); acc[7] = fmaf(w0, bfhi2f(v0.w), acc[7]);
    }
#pragma unroll
    for (int k = 0; k < 8; ++k) {
        acc[k] += __shfl_xor(acc[k], 16, 64);
        acc[k] += __shfl_xor(acc[k], 32, 64);
    }
    if (grp == 0) {
        unsigned short bv[8];
#pragma unroll
        for (int k = 0; k < 8; ++k) bv[k] = f2bf(acc[k]);
        *reinterpret_cast<uint4*>(outB + (size_t)wid * NHID + l16 * 8) =
            *reinterpret_cast<const uint4*>(bv);
    }
}

// ---------------- BN stats over bf16 buffer ----------------
__global__ __launch_bounds__(256) void stats_kernel(const unsigned short* __restrict__ h,
                                                    float* __restrict__ sums, int nrows) {
    const int t = threadIdx.x;
    const int cp = t & 63;        // column pair: cols 2cp, 2cp+1
    const int rg = t >> 6;        // row group 0..3
    float s0 = 0.f, s1 = 0.f, q0 = 0.f, q1 = 0.f;
    for (int r = blockIdx.x * 4 + rg; r < nrows; r += gridDim.x * 4) {
        const unsigned int v = *reinterpret_cast<const unsigned int*>(h + (size_t)r * NHID + cp * 2);
        const float a = bflo2f(v), b = bfhi2f(v);
        s0 += a; q0 = fmaf(a, a, q0);
        s1 += b; q1 = fmaf(b, b, q1);
    }
    __shared__ float ls[4][128], lq[4][128];
    ls[rg][cp * 2] = s0; ls[rg][cp * 2 + 1] = s1;
    lq[rg][cp * 2] = q0; lq[rg][cp * 2 + 1] = q1;
    __syncthreads();
    if (t < 128) {
        atomicAdd(&sums[t], ls[0][t] + ls[1][t] + ls[2][t] + ls[3][t]);
    } else {
        const int c = t - 128;
        atomicAdd(&sums[128 + c], lq[0][c] + lq[1][c] + lq[2][c] + lq[3][c]);
    }
}

// ---------------- GEMM2: bf16 A + fused finalize(BN1) + BN+ReLU at staging ----------------
__global__ __launch_bounds__(256) void mfma_gemm2(const unsigned short* __restrict__ Ab,
                                                  const unsigned short* __restrict__ Wtb,
                                                  const float* __restrict__ sums,
                                                  const float* __restrict__ gamma,
                                                  const float* __restrict__ beta,
                                                  unsigned short* __restrict__ C, int M) {
    constexpr int K = NHID;
    constexpr int NS = K / 32;
    constexpr int PADB = 40;
    __shared__ unsigned short As[2][64 * PADB];
    __shared__ float ssl[256];

    const int t = threadIdx.x;
    if (t < 128) {
        const float invN = 1.0f / (float)NNODES;
        const float mean = sums[t] * invN;
        const float var = sums[128 + t] * invN - mean * mean;
        const float scale = gamma[t] * rsqrtf(var + EPS);
        ssl[t] = scale;
        ssl[128 + t] = beta[t] - mean * scale;
    }
    __syncthreads();

    const int wid = t >> 6;
    const int lane = t & 63;
    const int wr = wid >> 1, wc = wid & 1;
    const int l15 = lane & 15, g = lane >> 4;
    const int R0 = blockIdx.x * 64;
    const int RW = R0 + wr * 32;
    const int srow = t >> 2;
    const int scol = (t & 3) * 8;

    f32x4 acc[2][4] = {};

    auto STAGE = [&](int s, int buf) {
        const int k0 = s * 32;
        int grow = R0 + srow;
        grow = grow < M ? grow : M - 1;
        const uint4 v = *reinterpret_cast<const uint4*>(Ab + (size_t)grow * K + k0 + scol);
        const float f[8] = {bflo2f(v.x), bfhi2f(v.x), bflo2f(v.y), bfhi2f(v.y),
                            bflo2f(v.z), bfhi2f(v.z), bflo2f(v.w), bfhi2f(v.w)};
        const int c0 = k0 + scol;
        unsigned short bv[8];
#pragma unroll
        for (int j = 0; j < 8; ++j)
            bv[j] = f2bf(fmaxf(fmaf(f[j], ssl[c0 + j], ssl[128 + c0 + j]), 0.f));
        *reinterpret_cast<uint4*>(&As[buf][srow * PADB + scol]) =
            *reinterpret_cast<const uint4*>(bv);
    };

    STAGE(0, 0);
    __syncthreads();

    for (int s = 0; s < NS; ++s) {
        if (s + 1 < NS) STAGE(s + 1, (s + 1) & 1);
        const unsigned short* ab = As[s & 1];
        short8v b[4];
#pragma unroll
        for (int n = 0; n < 4; ++n) {
            const int col = wc * 64 + n * 16 + l15;
            b[n] = *reinterpret_cast<const short8v*>(&Wtb[(size_t)col * K + s * 32 + g * 8]);
        }
        short8v a[2];
#pragma unroll
        for (int m = 0; m < 2; ++m) {
            const int row = wr * 32 + m * 16 + l15;
            a[m] = *reinterpret_cast<const short8v*>(&ab[row * PADB + g * 8]);
        }
#pragma unroll
        for (int m = 0; m < 2; ++m)
#pragma unroll
            for (int n = 0; n < 4; ++n)
                acc[m][n] = __builtin_amdgcn_mfma_f32_16x16x32_bf16(a[m], b[n], acc[m][n], 0, 0, 0);
        __syncthreads();
    }

#pragma unroll
    for (int m = 0; m < 2; ++m) {
#pragma unroll
        for (int q = 0; q < 4; ++q) {
            const int row = RW + m * 16 + g * 4 + q;
            if (row < M) {
                unsigned short* cp = C + (size_t)row * NHID + wc * 64 + l15;
#pragma unroll
                for (int n = 0; n < 4; ++n)
                    cp[n * 16] = f2bf(acc[m][n][q]);
            }
        }
    }
}

// ---------------- Final apply: fused finalize(BN2) + BN+ReLU, bf16 in / fp32 out ----------------
__global__ __launch_bounds__(256) void apply_kernel(const unsigned short* __restrict__ aggB,
                                                    const float* __restrict__ sums,
                                                    const float* __restrict__ gamma,
                                                    const float* __restrict__ beta,
                                                    float* __restrict__ out, int n8) {
    __shared__ float ss[256];
    const int t = threadIdx.x;
    if (t < 128) {
        const float invN = 1.0f / (float)NNODES;
        const float mean = sums[t] * invN;
        const float var = sums[128 + t] * invN - mean * mean;
        const float scale = gamma[t] * rsqrtf(var + EPS);
        ss[t] = scale;
        ss[128 + t] = beta[t] - mean * scale;
    }
    __syncthreads();
    const int idx = blockIdx.x * 256 + t;
    if (idx >= n8) return;
    const int c0 = (idx & 15) * 8;
    const uint4 v = reinterpret_cast<const uint4*>(aggB)[idx];
    const float f[8] = {bflo2f(v.x), bfhi2f(v.x), bflo2f(v.y), bfhi2f(v.y),
                        bflo2f(v.z), bfhi2f(v.z), bflo2f(v.w), bfhi2f(v.w)};
    float4 r0, r1;
    r0.x = fmaxf(fmaf(f[0], ss[c0],     ss[128 + c0]),     0.f);
    r0.y = fmaxf(fmaf(f[1], ss[c0 + 1], ss[128 + c0 + 1]), 0.f);
    r0.z = fmaxf(fmaf(f[2], ss[c0 + 2], ss[128 + c0 + 2]), 0.f);
    r0.w = fmaxf(fmaf(f[3], ss[c0 + 3], ss[128 + c0 + 3]), 0.f);
    r1.x = fmaxf(fmaf(f[4], ss[c0 + 4], ss[128 + c0 + 4]), 0.f);
    r1.y = fmaxf(fmaf(f[5], ss[c0 + 5], ss[128 + c0 + 5]), 0.f);
    r1.z = fmaxf(fmaf(f[6], ss[c0 + 6], ss[128 + c0 + 6]), 0.f);
    r1.w = fmaxf(fmaf(f[7], ss[c0 + 7], ss[128 + c0 + 7]), 0.f);
    reinterpret_cast<float4*>(out)[idx * 2] = r0;
    reinterpret_cast<float4*>(out)[idx * 2 + 1] = r1;
}

extern "C" void kernel_launch(void* const* d_in, const int* in_sizes, int n_in,
                              void* d_out, int out_size, void* d_ws, size_t ws_size,
                              hipStream_t stream) {
    const float* x   = (const float*)d_in[0];
    const int*   ei  = (const int*)d_in[1];
    const float* ew  = (const float*)d_in[2];
    const float* W1  = (const float*)d_in[3];
    const float* g1  = (const float*)d_in[5];
    const float* be1 = (const float*)d_in[6];
    const float* W2  = (const float*)d_in[7];
    const float* g2  = (const float*)d_in[9];
    const float* be2 = (const float*)d_in[10];
    float* out = (float*)d_out;

    const int M = NNODES;
    const int E = in_sizes[2];
    const int* src = ei;
    const int* dst = ei + E;

    // workspace layout (~82 MB)
    unsigned short* hb   = (unsigned short*)d_ws;             // M*128 bf16 (25.6 MB)
    unsigned short* aggB = hb + (size_t)M * NHID;             // M*128 bf16 (25.6 MB)
    int2* bstage = (int2*)(aggB + (size_t)M * NHID);          // NB2*BCAP2 (14.5 MB)
    int2* s_iw   = bstage + (size_t)NB2 * BCAP2;              // NB2*BCAP2 (14.5 MB)
    int2* row_be = s_iw + (size_t)NB2 * BCAP2;                // N (800 KB)
    int* gcur    = (int*)(row_be + NNODES);                   // NB2*CURPAD (12.5 KB)
    unsigned short* Wt1b = (unsigned short*)(gcur + NB2 * CURPAD);  // 256*128 bf16
    unsigned short* Wt2b = Wt1b + DIN * NHID;                 // 128*128 bf16
    float* sums  = (float*)(Wt2b + NHID * NHID);              // 512 (both layers)

    const int gemm_grid = (M + 63) / 64;
    const int n8 = M * NHID / 8;
    const int app_grid = (n8 + 255) / 256;
    const int agg_grid = (M * 64 + 255) / 256;
    const int part_grid = (E + PH - 1) / PH;
    const int prep_tot = DIN * NHID + NHID * NHID + NB2 * CURPAD + 512;

    // ---- Prep, then fused GEMM1 || partition ----
    prep_kernel<<<(prep_tot + 255) / 256, 256, 0, stream>>>(W1, W2, Wt1b, Wt2b, gcur, sums);
    gemm1_part_kernel<<<gemm_grid + part_grid, 256, 0, stream>>>(
        x, Wt1b, hb, M, gemm_grid, src, dst, ew, gcur, bstage, E);
    csr_kernel<<<NB2, 512, 0, stream>>>(gcur, bstage, row_be, s_iw);

    // ---- Layer 1 ----
    aggregate_kernel<<<agg_grid, 256, 0, stream>>>(hb, row_be, s_iw, aggB, M);
    stats_kernel<<<1024, 256, 0, stream>>>(aggB, sums, M);

    // ---- Layer 2 (finalize1 + BN1 + ReLU fused into GEMM2's staging) ----
    mfma_gemm2<<<gemm_grid, 256, 0, stream>>>(aggB, Wt2b, sums, g1, be1, hb, M);
    aggregate_kernel<<<agg_grid, 256, 0, stream>>>(hb, row_be, s_iw, aggB, M);
    stats_kernel<<<1024, 256, 0, stream>>>(aggB, sums + 256, M);
    apply_kernel<<<app_grid, 256, 0, stream>>>(aggB, sums + 256, g2, be2, out, n8);
}